// Round 7
// baseline (653.242 us; speedup 1.0000x reference)
//
#include <hip/hip_runtime.h>
#include <hip/hip_bf16.h>

static constexpr float kLog2 = 0.6931471805599453f;

__device__ __forceinline__ float sspf(float x) {
    return fmaxf(x, 0.0f) + __logf(1.0f + __expf(-fabsf(x))) - kLog2;
}

typedef __attribute__((ext_vector_type(8))) _Float16 half8;
typedef __attribute__((ext_vector_type(4))) _Float16 half4v;
typedef __attribute__((ext_vector_type(4))) float float4v;

// Feature permutation for h16 rows (producer: gemm_in, consumer: gather).
// For n = fh*64 + t*16 + q*4 + r: hperm(n) = fh*64 + (t>>1)*32 + q*8 + (t&1)*4 + r.
// Gather lane q of wave-half fh reads its 16 features for tiles t=0..3 as two
// contiguous half8 loads at h16 + jb + fh*64 + q*8 (+0, +32): the 4 q-lanes of
// one edge row cover one aligned 64B line per load instruction.
__device__ __forceinline__ int hperm(int n) {
    return ((n >> 6) << 6) | (((n >> 5) & 1) << 5) | (((n >> 2) & 3) << 3) |
           (((n >> 4) & 1) << 2) | (n & 3);
}

// ---------------- dense GEMMs (f16 MFMA 16x16x32, whole K in LDS) ----------
template <bool PERM, bool ACT, typename OUT>
__device__ __forceinline__ void gemm_mfma_body(const float* __restrict__ A,
                                               const float* __restrict__ B,
                                               const float* __restrict__ bias,
                                               OUT* __restrict__ C, int M,
                                               int blockid) {
    constexpr int LDH = 136;
    __shared__ _Float16 Als[64 * LDH];
    __shared__ _Float16 Bls[128 * LDH];
    const int tid = threadIdx.x;
    const int rowbase = blockid * 64;
#pragma unroll
    for (int j = 0; j < 8; ++j) {
        int idx = j * 256 + tid;
        int r = idx >> 5, c4 = (idx & 31) << 2;
        int rg = rowbase + r;
        rg = rg < M ? rg : (M - 1);
        float4 v = *(const float4*)(A + (size_t)rg * 128 + c4);
        half4v hv = {(_Float16)v.x, (_Float16)v.y, (_Float16)v.z, (_Float16)v.w};
        *(half4v*)&Als[r * LDH + c4] = hv;
    }
#pragma unroll
    for (int j = 0; j < 16; ++j) {
        int idx = j * 256 + tid;
        int r = idx >> 5, c4 = (idx & 31) << 2;
        float4 v = *(const float4*)(B + (size_t)r * 128 + c4);
        half4v hv = {(_Float16)v.x, (_Float16)v.y, (_Float16)v.z, (_Float16)v.w};
        *(half4v*)&Bls[r * LDH + c4] = hv;
    }
    __syncthreads();

    const int wave = tid >> 6, lane = tid & 63;
    const int l15 = lane & 15, q = lane >> 4;
    float4v acc[8];
#pragma unroll
    for (int nt = 0; nt < 8; ++nt) acc[nt] = (float4v){0.f, 0.f, 0.f, 0.f};
    const int am = wave * 16 + l15;
#pragma unroll
    for (int kk = 0; kk < 4; ++kk) {
        half8 af = *(const half8*)&Als[am * LDH + kk * 32 + q * 8];
#pragma unroll
        for (int nt = 0; nt < 8; ++nt) {
            half8 bfv = *(const half8*)&Bls[(nt * 16 + l15) * LDH + kk * 32 + q * 8];
            acc[nt] = __builtin_amdgcn_mfma_f32_16x16x32_f16(af, bfv, acc[nt], 0, 0, 0);
        }
    }
#pragma unroll
    for (int nt = 0; nt < 8; ++nt) {
        int n = nt * 16 + l15;
        float bv = bias[n];
        const int pn = PERM ? hperm(n) : n;
#pragma unroll
        for (int r = 0; r < 4; ++r) {
            int m = rowbase + wave * 16 + q * 4 + r;
            if (m < M) {
                float v = acc[nt][r] + bv;
                if (ACT) v = sspf(v);
                C[(size_t)m * 128 + pn] = (OUT)v;
            }
        }
    }
}

// counting half also records each edge's rank within its segment:
// rank[p] = old value of counts[idx_i[p]] -> fill needs NO atomics.
__global__ __launch_bounds__(256) void gemm_in_count_kernel(
    const float* __restrict__ A, const float* __restrict__ B,
    const float* __restrict__ bias, _Float16* __restrict__ C, int M,
    const int* __restrict__ idx_i, int* __restrict__ counts,
    int* __restrict__ rank, int P, int gemm_blocks) {
    if ((int)blockIdx.x < gemm_blocks) {
        gemm_mfma_body<true, false, _Float16>(A, B, bias, C, M, blockIdx.x);
    } else {
        const int nthr = (gridDim.x - gemm_blocks) * 256;
        for (int p = (blockIdx.x - gemm_blocks) * 256 + threadIdx.x; p < P;
             p += nthr)
            rank[p] = atomicAdd(&counts[idx_i[p]], 1);
    }
}

__global__ __launch_bounds__(256) void gemm_out_kernel(
    const float* __restrict__ A, const float* __restrict__ B,
    const float* __restrict__ bias, float* __restrict__ C, int M) {
    gemm_mfma_body<false, true, float>(A, B, bias, C, M, blockIdx.x);
}

// ---- one-kernel segment allocation: block scan + global bump (order-free) ----
__global__ __launch_bounds__(256) void alloc_starts_kernel(
    const int* __restrict__ counts, int* __restrict__ starts,
    int* __restrict__ gtot, int N) {
    __shared__ int s[256];
    __shared__ int base;
    const int t = threadIdx.x, g = blockIdx.x * 256 + t;
    const int c = g < N ? counts[g] : 0;
    s[t] = c;
    __syncthreads();
    for (int o = 1; o < 256; o <<= 1) {
        int v = t >= o ? s[t - o] : 0;
        __syncthreads();
        s[t] += v;
        __syncthreads();
    }
    if (t == 255) base = atomicAdd(gtot, s[255]);
    __syncthreads();
    const int excl = base + s[t] - c;
    if (g < N) starts[g] = excl;
}

// ---- fill48 (ATOMIC-FREE): one 48B record per edge in segment-sorted order.
//      pos = starts[idx_i[p]] + rank[p].
//      bytes [0..39] = f16 f_ij[0..19]; [40..43] = f32 rcut; [44..47] = jb. ----
__global__ __launch_bounds__(256) void fill48_kernel(
    const int* __restrict__ idx_i, const int* __restrict__ idx_j,
    const float* __restrict__ rcut, const float* __restrict__ f_ij,
    const int* __restrict__ starts, const int* __restrict__ rank,
    char* __restrict__ rec, int P) {
    int p = blockIdx.x * 256 + threadIdx.x;
    if (p >= P) return;
    const int pos = starts[idx_i[p]] + rank[p];
    const float* fr = f_ij + (size_t)p * 20;
    float4 v0 = *(const float4*)(fr + 0);
    float4 v1 = *(const float4*)(fr + 4);
    float4 v2 = *(const float4*)(fr + 8);
    float4 v3 = *(const float4*)(fr + 12);
    float4 v4 = *(const float4*)(fr + 16);
    half8 h0 = {(_Float16)v0.x, (_Float16)v0.y, (_Float16)v0.z, (_Float16)v0.w,
                (_Float16)v1.x, (_Float16)v1.y, (_Float16)v1.z, (_Float16)v1.w};
    half8 h1 = {(_Float16)v2.x, (_Float16)v2.y, (_Float16)v2.z, (_Float16)v2.w,
                (_Float16)v3.x, (_Float16)v3.y, (_Float16)v3.z, (_Float16)v3.w};
    _Float16 t4[4] = {(_Float16)v4.x, (_Float16)v4.y, (_Float16)v4.z,
                      (_Float16)v4.w};
    int4 r2;
    r2.x = *(const int*)&t4[0];
    r2.y = *(const int*)&t4[2];
    r2.z = __float_as_int(rcut[p]);
    r2.w = idx_j[p] << 7;
    char* dst = rec + (size_t)pos * 48;
    *(half8*)dst = h0;
    *(half8*)(dst + 16) = h1;
    *(int4*)(dst + 32) = r2;
}

// ---- gather: 2 waves per atom (64 features each), 16 edges per MFMA chunk.
//      Per chunk: one exec-masked dwordx4 record load (q<3; 16B quarter each),
//      rc/jb broadcast from the q2 lane via shfl, two half8 h-loads in hperm
//      full-line layout. Records prefetched 2 deep, h-rows 1 deep.
//      i0/units: atom-range split (diagnostic: halves per-dispatch duration
//      so hidden kernels can surface in the top-5 profile). ----
__global__ __launch_bounds__(256) void gather_rec_kernel(
    const char* __restrict__ rec, const float* __restrict__ Wf,
    const float* __restrict__ bf, const _Float16* __restrict__ h16,
    const int* __restrict__ starts, const int* __restrict__ counts,
    float* __restrict__ agg, int i0, int units) {
    const int lane = threadIdx.x & 63;
    const int gwave = (blockIdx.x * 256 + threadIdx.x) >> 6;
    const int nwaves = (gridDim.x * 256) >> 6;  // even -> u parity fixed/wave
    const int l15 = lane & 15, q = lane >> 4;
    const int fh = gwave & 1;       // feature half: tiles [fh*4, fh*4+4)
    const int fbase = fh * 64;

    // A-fragments: W_filter rows for this wave's 4 tiles, bias at k=20.
    half8 wfr[4];
#pragma unroll
    for (int t = 0; t < 4; ++t) {
        const int n = fbase + t * 16 + l15;
        const float* wr = Wf + (size_t)n * 20;
        float v[8];
#pragma unroll
        for (int j = 0; j < 8; ++j) {
            int k = q * 8 + j;
            v[j] = (k < 20) ? wr[k] : ((k == 20) ? bf[n] : 0.0f);
        }
        wfr[t] = (half8){(_Float16)v[0], (_Float16)v[1], (_Float16)v[2],
                         (_Float16)v[3], (_Float16)v[4], (_Float16)v[5],
                         (_Float16)v[6], (_Float16)v[7]};
    }
    const float4v zero = {0.f, 0.f, 0.f, 0.f};
    const _Float16* hws = h16 + fbase + q * 8;  // + jb per edge (hperm layout)

    for (int u = gwave; u < units; u += nwaves) {
        const int i = i0 + (u >> 1);
        const int s = __builtin_amdgcn_readfirstlane(starts[i]);
        const int cnt = __builtin_amdgcn_readfirstlane(counts[i]);
        const int e = s + cnt;
        float4v acc[4];
#pragma unroll
        for (int t = 0; t < 4; ++t) acc[t] = zero;

        if (cnt > 0) {
            // prologue: records for chunk0 and chunk1
            int4 r_c = {0, 0, 0, 0}, r_n = {0, 0, 0, 0};
            {
                int pos0 = min(s + l15, e - 1);
                if (q < 3) r_c = *(const int4*)(rec + (size_t)pos0 * 48 + q * 16);
            }
            if (s + 16 < e) {
                int pos1 = min(s + 16 + l15, e - 1);
                if (q < 3) r_n = *(const int4*)(rec + (size_t)pos1 * 48 + q * 16);
            } else {
                r_n = r_c;
            }
            // chunk0 rc/jb broadcast + h-row stage
            float rcv_c = __int_as_float(__shfl(r_c.z, 32 + l15, 64));
            int jb_c = __shfl(r_c.w, 32 + l15, 64);
            const _Float16* hp = hws + jb_c;
            half8 hv0_c = *(const half8*)hp;
            half8 hv1_c = *(const half8*)(hp + 32);

            for (int c0 = s; c0 < e; c0 += 16) {
                // next chunk's rc/jb + h-row (r_n arrived a chunk ago)
                float rcv_n = __int_as_float(__shfl(r_n.z, 32 + l15, 64));
                int jb_n = __shfl(r_n.w, 32 + l15, 64);
                half8 hv0_n = hv0_c, hv1_n = hv1_c;
                if (c0 + 16 < e) {
                    const _Float16* hp2 = hws + jb_n;
                    hv0_n = *(const half8*)hp2;
                    hv1_n = *(const half8*)(hp2 + 32);
                }
                // record two chunks ahead
                int4 r_n2 = r_n;
                if (c0 + 32 < e) {
                    int pos2 = min(c0 + 32 + l15, e - 1);
                    if (q < 3)
                        r_n2 = *(const int4*)(rec + (size_t)pos2 * 48 + q * 16);
                }
                // B-fragment from this chunk's record quarter
                half8 bfc = *(half8*)&r_c;   // q3: stays all-zero (never loaded)
                if (q == 2) {
                    bfc[4] = (_Float16)1.0f;  // bias multiplier at k=20
                    bfc[5] = (_Float16)0.0f;
                    bfc[6] = (_Float16)0.0f;
                    bfc[7] = (_Float16)0.0f;
                }
                const float rcm = (c0 + l15 < e) ? rcv_c : 0.0f;
#pragma unroll
                for (int t = 0; t < 4; ++t) {
                    float4v d = __builtin_amdgcn_mfma_f32_16x16x32_f16(
                        wfr[t], bfc, zero, 0, 0, 0);
                    const half8& hv = (t < 2) ? hv0_c : hv1_c;
                    const int hb = (t & 1) * 4;
#pragma unroll
                    for (int r = 0; r < 4; ++r) {
                        float w = sspf(d[r]) * rcm;
                        acc[t][r] = fmaf(w, (float)hv[hb + r], acc[t][r]);
                    }
                }
                // rotate pipeline registers
                r_c = r_n; r_n = r_n2;
                rcv_c = rcv_n;
                hv0_c = hv0_n; hv1_c = hv1_n;
            }
        }
        // reduce across the 16-edge (l15) dimension
#pragma unroll
        for (int m = 1; m <= 8; m <<= 1)
#pragma unroll
            for (int t = 0; t < 4; ++t)
#pragma unroll
                for (int r = 0; r < 4; ++r)
                    acc[t][r] += __shfl_xor(acc[t][r], m, 64);
        if (l15 == 0) {
#pragma unroll
            for (int t = 0; t < 4; ++t) {
                float4 o = {acc[t][0], acc[t][1], acc[t][2], acc[t][3]};
                *(float4*)(agg + (size_t)i * 128 + fbase + t * 16 + q * 4) = o;
            }
        }
    }
}

extern "C" void kernel_launch(void* const* d_in, const int* in_sizes, int n_in,
                              void* d_out, int out_size, void* d_ws, size_t ws_size,
                              hipStream_t stream) {
    const float* x     = (const float*)d_in[0];
    const float* f_ij  = (const float*)d_in[1];
    const int*   idx_i = (const int*)d_in[2];
    const int*   idx_j = (const int*)d_in[3];
    const float* rcut  = (const float*)d_in[4];
    const float* W_in  = (const float*)d_in[5];
    const float* b_in  = (const float*)d_in[6];
    const float* W_f   = (const float*)d_in[7];
    const float* b_f   = (const float*)d_in[8];
    const float* W_out = (const float*)d_in[9];
    const float* b_out = (const float*)d_in[10];

    const int N = in_sizes[0] / 128;  // 50000
    const int P = in_sizes[2];        // 1600000

    // workspace layout (16B-aligned chunks); ~97 MB total
    char* ws = (char*)d_ws;
    size_t off = 0;
    auto alloc = [&](size_t bytes) {
        void* ptr = ws + off;
        off += (bytes + 15) & ~(size_t)15;
        return ptr;
    };
    int* counts  = (int*)alloc((size_t)N * 4 + 16);  // gtot rides at counts[N..]
    int* gtot    = counts + N;
    int* starts  = (int*)alloc((size_t)N * 4);
    int* rank    = (int*)alloc((size_t)P * 4);
    _Float16* h16 = (_Float16*)alloc((size_t)N * 128 * 2);
    char* rec    = (char*)alloc((size_t)P * 48 + 64);

    float* agg = (float*)d_out;  // gather writes agg f32; gemm_out runs in-place

    const int mblocks = (N + 63) / 64;  // 782
    const int cblocks = 768;
    const int NB = (N + 255) / 256;
    const int Nh = N / 2;

    hipMemsetAsync(counts, 0, (size_t)N * 4 + 16, stream);  // counts + gtot
    gemm_in_count_kernel<<<mblocks + cblocks, 256, 0, stream>>>(
        x, W_in, b_in, h16, N, idx_i, counts, rank, P, mblocks);
    alloc_starts_kernel<<<NB, 256, 0, stream>>>(counts, starts, gtot, N);
    fill48_kernel<<<(P + 255) / 256, 256, 0, stream>>>(
        idx_i, idx_j, rcut, f_ij, starts, rank, rec, P);
    gather_rec_kernel<<<4096, 256, 0, stream>>>(
        rec, W_f, b_f, h16, starts, counts, agg, 0, 2 * Nh);
    gather_rec_kernel<<<4096, 256, 0, stream>>>(
        rec, W_f, b_f, h16, starts, counts, agg, Nh, 2 * (N - Nh));
    gemm_out_kernel<<<mblocks, 256, 0, stream>>>(agg, W_out, b_out, (float*)d_out, N);
}